// Round 1
// baseline (403.809 us; speedup 1.0000x reference)
//
#include <hip/hip_runtime.h>
#include <hip/hip_bf16.h>
#include <cmath>

#define BETA 0.3f
#define LAMBDA_PHY 0.15f

#define BM 128
#define BN 128
#define BK 32

typedef __bf16 bf16x8 __attribute__((ext_vector_type(8)));
typedef float f32x4 __attribute__((ext_vector_type(4)));

__device__ __forceinline__ unsigned short f2bf_rn(float f) {
    unsigned int u = __builtin_bit_cast(unsigned int, f);
    return (unsigned short)((u + 0x7FFFu + ((u >> 16) & 1u)) >> 16);
}

__device__ __forceinline__ float softplus_f(float x) {
    return fmaxf(x, 0.0f) + __logf(1.0f + __expf(-fabsf(x)));
}

__device__ __forceinline__ float smooth_l1_f(float d) {
    float ad = fabsf(d);
    return (ad < BETA) ? (0.5f / BETA) * d * d : (ad - 0.5f * BETA);
}

// ---------------------------------------------------------------------------
// Kernel 1: adjacency (int32 ZxZ) -> bf16 mask (ZxZ, row-major over n = K-contig)
//           + inv_safe_deg[z] + hasnb[z]
__global__ void k_prep(const int* __restrict__ adj, unsigned short* __restrict__ maskbf,
                       float* __restrict__ invdeg, float* __restrict__ hasnb, int Z) {
    int z = blockIdx.x;
    int t = threadIdx.x;
    const int* row = adj + (size_t)z * Z;
    unsigned short* mrow = maskbf + (size_t)z * Z;
    int cnt = 0;
    for (int n = t; n < Z; n += blockDim.x) {
        int a = (row[n] > 0);
        mrow[n] = a ? (unsigned short)0x3F80 : (unsigned short)0;  // bf16 1.0 / 0.0
        cnt += a;
    }
    for (int o = 32; o; o >>= 1) cnt += __shfl_down(cnt, o);
    __shared__ int rs[4];
    int lane = t & 63, wave = t >> 6;
    if (lane == 0) rs[wave] = cnt;
    __syncthreads();
    if (t == 0) {
        int deg = rs[0] + rs[1] + rs[2] + rs[3];
        invdeg[z] = (deg > 0) ? 1.0f / (float)deg : 1.0f;
        hasnb[z]  = (deg > 0) ? 1.0f : 0.0f;
    }
}

// ---------------------------------------------------------------------------
// Kernel 2: fp32 -> bf16 (RN), 8 elems/thread, vectorized
__global__ void k_conv(const float* __restrict__ src, uint4* __restrict__ dst, long n8) {
    long i = (long)blockIdx.x * blockDim.x + threadIdx.x;
    long stride = (long)gridDim.x * blockDim.x;
    for (; i < n8; i += stride) {
        const float4* s = (const float4*)(src + i * 8);
        float4 a = s[0], b = s[1];
        uint4 o;
        o.x = (unsigned)f2bf_rn(a.x) | ((unsigned)f2bf_rn(a.y) << 16);
        o.y = (unsigned)f2bf_rn(a.z) | ((unsigned)f2bf_rn(a.w) << 16);
        o.z = (unsigned)f2bf_rn(b.x) | ((unsigned)f2bf_rn(b.y) << 16);
        o.w = (unsigned)f2bf_rn(b.z) | ((unsigned)f2bf_rn(b.w) << 16);
        dst[i] = o;
    }
}

// ---------------------------------------------------------------------------
// Kernel 3: bf16 GEMM (B^T layout) with fused softplus/smooth-L1 epilogue.
// A = Cbf [M][K] (temps), B = maskbf [N][K]. D[b][z] = sum_k A[b][k]*mask[z][k].
__global__ __launch_bounds__(256) void k_gemm(
    const unsigned short* __restrict__ Abf,
    const unsigned short* __restrict__ Bbf,
    const float* __restrict__ preds,
    const float* __restrict__ targets,
    const float* __restrict__ ctemps,
    const float* __restrict__ invdeg,
    const float* __restrict__ hasnb,
    float* __restrict__ partials,
    int M, int N, int K)
{
    __shared__ unsigned short As[BM * BK];
    __shared__ unsigned short Bs[BN * BK];

    const int bid = blockIdx.x;
    const int ntiles = N / BN;
    const int mt = bid / ntiles;          // consecutive bids share the A panel
    const int nt = bid % ntiles;
    const int row0 = mt * BM;
    const int col0 = nt * BN;
    const int t = threadIdx.x;
    const int lane = t & 63;
    const int wave = t >> 6;
    const int wm = wave >> 1;             // 2x2 wave grid, each wave 64x64 out
    const int wn = wave & 1;
    const int fr = lane & 15;
    const int fq = lane >> 4;

    f32x4 acc[4][4];
#pragma unroll
    for (int m = 0; m < 4; ++m)
#pragma unroll
        for (int n = 0; n < 4; ++n)
            acc[m][n] = (f32x4){0.f, 0.f, 0.f, 0.f};

    const unsigned short* Ab = Abf + (size_t)row0 * K;
    const unsigned short* Bb = Bbf + (size_t)col0 * K;

    const int sr = t >> 2;                // staging: thread -> (row, col8)
    const int sc = (t & 3) * 8;           // LDS dest linear in t -> lane*16B per wave

    for (int k0 = 0; k0 < K; k0 += BK) {
        __syncthreads();
        __builtin_amdgcn_global_load_lds(
            (const __attribute__((address_space(1))) void*)(Ab + (size_t)sr * K + k0 + sc),
            (__attribute__((address_space(3))) void*)(&As[sr * BK + sc]), 16, 0, 0);
        __builtin_amdgcn_global_load_lds(
            (const __attribute__((address_space(1))) void*)(Ab + (size_t)(sr + 64) * K + k0 + sc),
            (__attribute__((address_space(3))) void*)(&As[(sr + 64) * BK + sc]), 16, 0, 0);
        __builtin_amdgcn_global_load_lds(
            (const __attribute__((address_space(1))) void*)(Bb + (size_t)sr * K + k0 + sc),
            (__attribute__((address_space(3))) void*)(&Bs[sr * BK + sc]), 16, 0, 0);
        __builtin_amdgcn_global_load_lds(
            (const __attribute__((address_space(1))) void*)(Bb + (size_t)(sr + 64) * K + k0 + sc),
            (__attribute__((address_space(3))) void*)(&Bs[(sr + 64) * BK + sc]), 16, 0, 0);
        __syncthreads();

        bf16x8 af[4], bfv[4];
#pragma unroll
        for (int m = 0; m < 4; ++m)
            af[m] = *(const bf16x8*)&As[(wm * 64 + m * 16 + fr) * BK + fq * 8];
#pragma unroll
        for (int n = 0; n < 4; ++n)
            bfv[n] = *(const bf16x8*)&Bs[(wn * 64 + n * 16 + fr) * BK + fq * 8];
#pragma unroll
        for (int m = 0; m < 4; ++m)
#pragma unroll
            for (int n = 0; n < 4; ++n)
                acc[m][n] = __builtin_amdgcn_mfma_f32_16x16x32_bf16(af[m], bfv[n], acc[m][n], 0, 0, 0);
    }

    // Fused epilogue: C/D layout col=lane&15, row=(lane>>4)*4+reg  [m89/m91]
    float vsum = 0.f, ssum = 0.f;
#pragma unroll
    for (int n = 0; n < 4; ++n) {
        const int z = col0 + wn * 64 + n * 16 + fr;
        const float idg = invdeg[z];
        const float hnb = hasnb[z];
#pragma unroll
        for (int m = 0; m < 4; ++m) {
            const int rb = row0 + wm * 64 + m * 16 + fq * 4;
#pragma unroll
            for (int j = 0; j < 4; ++j) {
                const size_t idx = (size_t)(rb + j) * N + z;
                float avg = acc[m][n][j] * idg;
                float c = ctemps[idx];
                float p = preds[idx];
                float tg = targets[idx];
                float x = (c - avg) * (p - c);
                vsum += softplus_f(x) * hnb;
                ssum += smooth_l1_f(p - tg);
            }
        }
    }
    for (int o = 32; o; o >>= 1) { vsum += __shfl_down(vsum, o); ssum += __shfl_down(ssum, o); }
    __shared__ float rv[4], rsm[4];
    if (lane == 0) { rv[wave] = vsum; rsm[wave] = ssum; }
    __syncthreads();
    if (t == 0) {
        partials[2 * (size_t)bid]     = rv[0] + rv[1] + rv[2] + rv[3];
        partials[2 * (size_t)bid + 1] = rsm[0] + rsm[1] + rsm[2] + rsm[3];
    }
}

// ---------------------------------------------------------------------------
// Kernel 4: deterministic fixed-order final reduction
__global__ void k_finalize(const float* __restrict__ partials, int nblk,
                           float* __restrict__ out, float invBZ) {
    __shared__ float sv[256], ss[256];
    int t = threadIdx.x;
    float v = 0.f, s = 0.f;
    for (int i = t; i < nblk; i += 256) { v += partials[2 * (size_t)i]; s += partials[2 * (size_t)i + 1]; }
    sv[t] = v; ss[t] = s;
    __syncthreads();
    for (int o = 128; o; o >>= 1) {
        if (t < o) { sv[t] += sv[t + o]; ss[t] += ss[t + o]; }
        __syncthreads();
    }
    if (t == 0) {
        float phys = sv[0] * invBZ;
        float pred = ss[0] * invBZ;
        out[0] = pred + LAMBDA_PHY * phys;
        out[1] = phys;
    }
}

// ---------------------------------------------------------------------------
// Fallback path (only if ws too small / odd shapes): fp32, atomics into ws[0..1]
__global__ void k_zero2(float* p) { if (threadIdx.x < 2) p[threadIdx.x] = 0.f; }

__global__ void k_fallback(const float* __restrict__ preds, const float* __restrict__ targets,
                           const float* __restrict__ ctemps, const int* __restrict__ adj,
                           float* __restrict__ acc2, int B, int Z) {
    extern __shared__ float crow[];
    int nzb = (Z + 255) / 256;
    int b = blockIdx.x / nzb;
    int zb = blockIdx.x % nzb;
    int t = threadIdx.x;
    const float* cr = ctemps + (size_t)b * Z;
    for (int n = t; n < Z; n += 256) crow[n] = cr[n];
    __syncthreads();
    int z = zb * 256 + t;
    float vsum = 0.f, ssum = 0.f;
    if (z < Z) {
        const int* arow = adj + (size_t)z * Z;
        float sum = 0.f; int deg = 0;
        for (int n = 0; n < Z; ++n) {
            if (arow[n] > 0) { sum += crow[n]; ++deg; }
        }
        float avg = (deg > 0) ? sum / (float)deg : 0.f;
        float c = crow[z];
        size_t idx = (size_t)b * Z + z;
        float p = preds[idx];
        float x = (c - avg) * (p - c);
        vsum = (deg > 0) ? softplus_f(x) : 0.f;
        ssum = smooth_l1_f(p - targets[idx]);
    }
    for (int o = 32; o; o >>= 1) { vsum += __shfl_down(vsum, o); ssum += __shfl_down(ssum, o); }
    __shared__ float rv[4], rs2[4];
    int lane = t & 63, wave = t >> 6;
    if (lane == 0) { rv[wave] = vsum; rs2[wave] = ssum; }
    __syncthreads();
    if (t == 0) {
        atomicAdd(&acc2[0], rv[0] + rv[1] + rv[2] + rv[3]);
        atomicAdd(&acc2[1], rs2[0] + rs2[1] + rs2[2] + rs2[3]);
    }
}

// ---------------------------------------------------------------------------
extern "C" void kernel_launch(void* const* d_in, const int* in_sizes, int n_in,
                              void* d_out, int out_size, void* d_ws, size_t ws_size,
                              hipStream_t stream) {
    const float* preds   = (const float*)d_in[0];
    const float* targets = (const float*)d_in[1];
    const float* ctemps  = (const float*)d_in[2];
    const int*   adj     = (const int*)d_in[3];
    float* out = (float*)d_out;

    long zz = in_sizes[3];
    int Z = (int)llround(sqrt((double)zz));
    int B = in_sizes[1] / Z;

    size_t off = 0;
    size_t maskOff = off; off += (size_t)Z * Z * 2;
    size_t cbfOff  = off; off += (size_t)B * Z * 2;
    size_t idgOff  = off; off += (size_t)Z * 4;
    size_t hnbOff  = off; off += (size_t)Z * 4;
    int nblk = (Z > 0 && B > 0 && (B % BM) == 0 && (Z % BN) == 0) ? (B / BM) * (Z / BN) : 0;
    size_t partOff = off; off += (size_t)(nblk > 0 ? nblk : 1) * 2 * 4;

    bool main_ok = (B % BM == 0) && (Z % BN == 0) && (Z % BK == 0) && (ws_size >= off);

    float invBZ = (float)(1.0 / ((double)B * (double)Z));

    if (main_ok) {
        char* ws = (char*)d_ws;
        unsigned short* maskbf = (unsigned short*)(ws + maskOff);
        unsigned short* cbf    = (unsigned short*)(ws + cbfOff);
        float* idg      = (float*)(ws + idgOff);
        float* hnb      = (float*)(ws + hnbOff);
        float* partials = (float*)(ws + partOff);

        k_prep<<<Z, 256, 0, stream>>>(adj, maskbf, idg, hnb, Z);
        long n8 = (long)B * Z / 8;
        k_conv<<<2048, 256, 0, stream>>>(ctemps, (uint4*)cbf, n8);
        k_gemm<<<nblk, 256, 0, stream>>>(cbf, maskbf, preds, targets, ctemps, idg, hnb, partials, B, Z, Z);
        k_finalize<<<1, 256, 0, stream>>>(partials, nblk, out, invBZ);
    } else {
        float* acc2 = (float*)d_ws;
        k_zero2<<<1, 64, 0, stream>>>(acc2);
        int nzb = (Z + 255) / 256;
        k_fallback<<<B * nzb, 256, (size_t)Z * 4, stream>>>(preds, targets, ctemps, adj, acc2, B, Z);
        k_finalize<<<1, 256, 0, stream>>>(acc2, 1, out, invBZ);
    }
}

// Round 2
// 401.286 us; speedup vs baseline: 1.0063x; 1.0063x over previous
//
#include <hip/hip_runtime.h>
#include <hip/hip_bf16.h>
#include <cmath>

#define BETA 0.3f
#define LAMBDA_PHY 0.15f

#define BM 256
#define BN 256
#define BK 64
#define NTHREADS 512

typedef __bf16 bf16x8 __attribute__((ext_vector_type(8)));
typedef float f32x4 __attribute__((ext_vector_type(4)));

__device__ __forceinline__ unsigned short f2bf_rn(float f) {
    unsigned int u = __builtin_bit_cast(unsigned int, f);
    return (unsigned short)((u + 0x7FFFu + ((u >> 16) & 1u)) >> 16);
}

__device__ __forceinline__ float softplus_f(float x) {
    return fmaxf(x, 0.0f) + __logf(1.0f + __expf(-fabsf(x)));
}

__device__ __forceinline__ float smooth_l1_f(float d) {
    float ad = fabsf(d);
    return (ad < BETA) ? (0.5f / BETA) * d * d : (ad - 0.5f * BETA);
}

// ---------------------------------------------------------------------------
// Kernel 1: adjacency (int32 ZxZ) -> bf16 mask (ZxZ, K-contig) + invdeg + hasnb
__global__ void k_prep(const int* __restrict__ adj, unsigned short* __restrict__ maskbf,
                       float* __restrict__ invdeg, float* __restrict__ hasnb, int Z) {
    int z = blockIdx.x;
    int t = threadIdx.x;
    const int* row = adj + (size_t)z * Z;
    unsigned short* mrow = maskbf + (size_t)z * Z;
    int cnt = 0;
    for (int n = t; n < Z; n += blockDim.x) {
        int a = (row[n] > 0);
        mrow[n] = a ? (unsigned short)0x3F80 : (unsigned short)0;  // bf16 1.0 / 0.0
        cnt += a;
    }
    for (int o = 32; o; o >>= 1) cnt += __shfl_down(cnt, o);
    __shared__ int rs[4];
    int lane = t & 63, wave = t >> 6;
    if (lane == 0) rs[wave] = cnt;
    __syncthreads();
    if (t == 0) {
        int deg = rs[0] + rs[1] + rs[2] + rs[3];
        invdeg[z] = (deg > 0) ? 1.0f / (float)deg : 1.0f;
        hasnb[z]  = (deg > 0) ? 1.0f : 0.0f;
    }
}

// ---------------------------------------------------------------------------
// Kernel 2: fp32 -> bf16 (RN), 8 elems/thread, vectorized
__global__ void k_conv(const float* __restrict__ src, uint4* __restrict__ dst, long n8) {
    long i = (long)blockIdx.x * blockDim.x + threadIdx.x;
    long stride = (long)gridDim.x * blockDim.x;
    for (; i < n8; i += stride) {
        const float4* s = (const float4*)(src + i * 8);
        float4 a = s[0], b = s[1];
        uint4 o;
        o.x = (unsigned)f2bf_rn(a.x) | ((unsigned)f2bf_rn(a.y) << 16);
        o.y = (unsigned)f2bf_rn(a.z) | ((unsigned)f2bf_rn(a.w) << 16);
        o.z = (unsigned)f2bf_rn(b.x) | ((unsigned)f2bf_rn(b.y) << 16);
        o.w = (unsigned)f2bf_rn(b.z) | ((unsigned)f2bf_rn(b.w) << 16);
        dst[i] = o;
    }
}

// ---------------------------------------------------------------------------
// Kernel 3: 256x256 bf16 GEMM, 2-phase double-buffered (T3 minimum recipe),
// XCD-bijective block swizzle (T1), fused softplus/smooth-L1 epilogue.
// A = Cbf [M][K] (temps), B = maskbf [N][K]. D[b][z] = sum_k A[b][k]*mask[z][k].
__global__ __launch_bounds__(NTHREADS, 2) void k_gemm(
    const unsigned short* __restrict__ Abf,
    const unsigned short* __restrict__ Bbf,
    const float* __restrict__ preds,
    const float* __restrict__ targets,
    const float* __restrict__ ctemps,
    const float* __restrict__ invdeg,
    const float* __restrict__ hasnb,
    float* __restrict__ partials,
    int M, int N, int K)
{
    __shared__ unsigned short As[2][BM * BK];
    __shared__ unsigned short Bs[2][BN * BK];

    const int nwg = gridDim.x;
    const int ob = blockIdx.x;
    // T1: bijective XCD swizzle (nwg % 8 == 0 in the main path)
    const int bid = (nwg % 8 == 0) ? ((ob % 8) * (nwg / 8) + ob / 8) : ob;
    const int ntiles = N / BN;
    const int mt = bid / ntiles;
    const int nt = bid % ntiles;
    const int row0 = mt * BM;
    const int col0 = nt * BN;
    const int t = threadIdx.x;
    const int lane = t & 63;
    const int wave = t >> 6;
    const int wm = wave >> 2;             // 2x4 wave grid; each wave 128x64 out
    const int wn = wave & 3;
    const int fr = lane & 15;
    const int fq = lane >> 4;

    f32x4 acc[8][4];
#pragma unroll
    for (int m = 0; m < 8; ++m)
#pragma unroll
        for (int n = 0; n < 4; ++n)
            acc[m][n] = (f32x4){0.f, 0.f, 0.f, 0.f};

    const unsigned short* Ab = Abf + (size_t)row0 * K;
    const unsigned short* Bb = Bbf + (size_t)col0 * K;

    const int sr3 = t >> 3;               // staging row within 64-row group
    const int sc8 = (t & 7) * 8;          // staging col (elements)

#define STAGE(buf, kt)                                                                          \
    do {                                                                                        \
        const int kq_ = (kt) * BK;                                                              \
        _Pragma("unroll")                                                                       \
        for (int i_ = 0; i_ < 4; ++i_) {                                                        \
            __builtin_amdgcn_global_load_lds(                                                   \
                (const __attribute__((address_space(1))) void*)(Ab + (size_t)(i_ * 64 + sr3) * K + kq_ + sc8), \
                (__attribute__((address_space(3))) void*)(&As[buf][(i_ * 64 + sr3) * BK + sc8]), \
                16, 0, 0);                                                                      \
        }                                                                                       \
        _Pragma("unroll")                                                                       \
        for (int i_ = 0; i_ < 4; ++i_) {                                                        \
            __builtin_amdgcn_global_load_lds(                                                   \
                (const __attribute__((address_space(1))) void*)(Bb + (size_t)(i_ * 64 + sr3) * K + kq_ + sc8), \
                (__attribute__((address_space(3))) void*)(&Bs[buf][(i_ * 64 + sr3) * BK + sc8]), \
                16, 0, 0);                                                                      \
        }                                                                                       \
    } while (0)

    const int nk = K / BK;
    int cur = 0;
    STAGE(0, 0);
    __syncthreads();  // drains vmcnt(0) before barrier

    for (int kt = 0; kt < nk; ++kt) {
        if (kt + 1 < nk) STAGE(cur ^ 1, kt + 1);   // prefetch overlaps MFMA below
#pragma unroll
        for (int kk = 0; kk < 2; ++kk) {
            bf16x8 af[8], bv[4];
#pragma unroll
            for (int m = 0; m < 8; ++m)
                af[m] = *(const bf16x8*)&As[cur][(wm * 128 + m * 16 + fr) * BK + kk * 32 + fq * 8];
#pragma unroll
            for (int n = 0; n < 4; ++n)
                bv[n] = *(const bf16x8*)&Bs[cur][(wn * 64 + n * 16 + fr) * BK + kk * 32 + fq * 8];
#pragma unroll
            for (int m = 0; m < 8; ++m)
#pragma unroll
                for (int n = 0; n < 4; ++n)
                    acc[m][n] = __builtin_amdgcn_mfma_f32_16x16x32_bf16(af[m], bv[n], acc[m][n], 0, 0, 0);
        }
        __syncthreads();  // drains this block's stage writes + all waves' reads
        cur ^= 1;
    }
#undef STAGE

    // Fused epilogue: C/D layout col=lane&15, row=(lane>>4)*4+reg  [m89/m91]
    float vsum = 0.f, ssum = 0.f;
#pragma unroll
    for (int n = 0; n < 4; ++n) {
        const int z = col0 + wn * 64 + n * 16 + fr;
        const float idg = invdeg[z];
        const float hnb = hasnb[z];
#pragma unroll
        for (int m = 0; m < 8; ++m) {
            const int rb = row0 + wm * 128 + m * 16 + fq * 4;
#pragma unroll
            for (int j = 0; j < 4; ++j) {
                const size_t idx = (size_t)(rb + j) * N + z;
                float avg = acc[m][n][j] * idg;
                float c = ctemps[idx];
                float p = preds[idx];
                float tg = targets[idx];
                float x = (c - avg) * (p - c);
                vsum += softplus_f(x) * hnb;
                ssum += smooth_l1_f(p - tg);
            }
        }
    }
    for (int o = 32; o; o >>= 1) { vsum += __shfl_down(vsum, o); ssum += __shfl_down(ssum, o); }
    __shared__ float rv[8], rsm[8];
    if (lane == 0) { rv[wave] = vsum; rsm[wave] = ssum; }
    __syncthreads();
    if (t == 0) {
        float v = 0.f, s = 0.f;
#pragma unroll
        for (int w = 0; w < 8; ++w) { v += rv[w]; s += rsm[w]; }
        partials[2 * (size_t)ob]     = v;   // original blockIdx -> unique slot
        partials[2 * (size_t)ob + 1] = s;
    }
}

// ---------------------------------------------------------------------------
// Kernel 4: deterministic fixed-order final reduction
__global__ void k_finalize(const float* __restrict__ partials, int nblk,
                           float* __restrict__ out, float invBZ) {
    __shared__ float sv[256], ss[256];
    int t = threadIdx.x;
    float v = 0.f, s = 0.f;
    for (int i = t; i < nblk; i += 256) { v += partials[2 * (size_t)i]; s += partials[2 * (size_t)i + 1]; }
    sv[t] = v; ss[t] = s;
    __syncthreads();
    for (int o = 128; o; o >>= 1) {
        if (t < o) { sv[t] += sv[t + o]; ss[t] += ss[t + o]; }
        __syncthreads();
    }
    if (t == 0) {
        float phys = sv[0] * invBZ;
        float pred = ss[0] * invBZ;
        out[0] = pred + LAMBDA_PHY * phys;
        out[1] = phys;
    }
}

// ---------------------------------------------------------------------------
// Fallback path (only if ws too small / odd shapes): fp32, atomics into ws[0..1]
__global__ void k_zero2(float* p) { if (threadIdx.x < 2) p[threadIdx.x] = 0.f; }

__global__ void k_fallback(const float* __restrict__ preds, const float* __restrict__ targets,
                           const float* __restrict__ ctemps, const int* __restrict__ adj,
                           float* __restrict__ acc2, int B, int Z) {
    extern __shared__ float crow[];
    int nzb = (Z + 255) / 256;
    int b = blockIdx.x / nzb;
    int zb = blockIdx.x % nzb;
    int t = threadIdx.x;
    const float* cr = ctemps + (size_t)b * Z;
    for (int n = t; n < Z; n += 256) crow[n] = cr[n];
    __syncthreads();
    int z = zb * 256 + t;
    float vsum = 0.f, ssum = 0.f;
    if (z < Z) {
        const int* arow = adj + (size_t)z * Z;
        float sum = 0.f; int deg = 0;
        for (int n = 0; n < Z; ++n) {
            if (arow[n] > 0) { sum += crow[n]; ++deg; }
        }
        float avg = (deg > 0) ? sum / (float)deg : 0.f;
        float c = crow[z];
        size_t idx = (size_t)b * Z + z;
        float p = preds[idx];
        float x = (c - avg) * (p - c);
        vsum = (deg > 0) ? softplus_f(x) : 0.f;
        ssum = smooth_l1_f(p - targets[idx]);
    }
    for (int o = 32; o; o >>= 1) { vsum += __shfl_down(vsum, o); ssum += __shfl_down(ssum, o); }
    __shared__ float rv[4], rs2[4];
    int lane = t & 63, wave = t >> 6;
    if (lane == 0) { rv[wave] = vsum; rs2[wave] = ssum; }
    __syncthreads();
    if (t == 0) {
        atomicAdd(&acc2[0], rv[0] + rv[1] + rv[2] + rv[3]);
        atomicAdd(&acc2[1], rs2[0] + rs2[1] + rs2[2] + rs2[3]);
    }
}

// ---------------------------------------------------------------------------
extern "C" void kernel_launch(void* const* d_in, const int* in_sizes, int n_in,
                              void* d_out, int out_size, void* d_ws, size_t ws_size,
                              hipStream_t stream) {
    const float* preds   = (const float*)d_in[0];
    const float* targets = (const float*)d_in[1];
    const float* ctemps  = (const float*)d_in[2];
    const int*   adj     = (const int*)d_in[3];
    float* out = (float*)d_out;

    long zz = in_sizes[3];
    int Z = (int)llround(sqrt((double)zz));
    int B = in_sizes[1] / Z;

    size_t off = 0;
    size_t maskOff = off; off += (size_t)Z * Z * 2;
    size_t cbfOff  = off; off += (size_t)B * Z * 2;
    size_t idgOff  = off; off += (size_t)Z * 4;
    size_t hnbOff  = off; off += (size_t)Z * 4;
    int nblk = (Z > 0 && B > 0 && (B % BM) == 0 && (Z % BN) == 0) ? (B / BM) * (Z / BN) : 0;
    size_t partOff = off; off += (size_t)(nblk > 0 ? nblk : 1) * 2 * 4;

    bool main_ok = (B % BM == 0) && (Z % BN == 0) && (Z % BK == 0) && (ws_size >= off);

    float invBZ = (float)(1.0 / ((double)B * (double)Z));

    if (main_ok) {
        char* ws = (char*)d_ws;
        unsigned short* maskbf = (unsigned short*)(ws + maskOff);
        unsigned short* cbf    = (unsigned short*)(ws + cbfOff);
        float* idg      = (float*)(ws + idgOff);
        float* hnb      = (float*)(ws + hnbOff);
        float* partials = (float*)(ws + partOff);

        k_prep<<<Z, 256, 0, stream>>>(adj, maskbf, idg, hnb, Z);
        long n8 = (long)B * Z / 8;
        k_conv<<<2048, 256, 0, stream>>>(ctemps, (uint4*)cbf, n8);
        k_gemm<<<nblk, NTHREADS, 0, stream>>>(cbf, maskbf, preds, targets, ctemps, idg, hnb, partials, B, Z, Z);
        k_finalize<<<1, 256, 0, stream>>>(partials, nblk, out, invBZ);
    } else {
        float* acc2 = (float*)d_ws;
        k_zero2<<<1, 64, 0, stream>>>(acc2);
        int nzb = (Z + 255) / 256;
        k_fallback<<<B * nzb, 256, (size_t)Z * 4, stream>>>(preds, targets, ctemps, adj, acc2, B, Z);
        k_finalize<<<1, 256, 0, stream>>>(acc2, 1, out, invBZ);
    }
}

// Round 3
// 380.510 us; speedup vs baseline: 1.0612x; 1.0546x over previous
//
#include <hip/hip_runtime.h>
#include <hip/hip_bf16.h>
#include <cmath>

#define BETA 0.3f
#define LAMBDA_PHY 0.15f

#define BM 256
#define BN 256
#define BK 64
#define NT 512

typedef __bf16 bf16x8 __attribute__((ext_vector_type(8)));
typedef float f32x4 __attribute__((ext_vector_type(4)));

#define AS1 __attribute__((address_space(1)))
#define AS3 __attribute__((address_space(3)))

#define FENCE() asm volatile("" ::: "memory")
#define BARRIER() do { FENCE(); __builtin_amdgcn_s_barrier(); FENCE(); } while (0)
#define WAITV6() asm volatile("s_waitcnt vmcnt(6)" ::: "memory")
#define WAITV4() asm volatile("s_waitcnt vmcnt(4)" ::: "memory")
#define WAITV0() asm volatile("s_waitcnt vmcnt(0)" ::: "memory")

__device__ __forceinline__ unsigned short f2bf_rn(float f) {
    unsigned int u = __builtin_bit_cast(unsigned int, f);
    return (unsigned short)((u + 0x7FFFu + ((u >> 16) & 1u)) >> 16);
}

__device__ __forceinline__ float bf2f(unsigned short u) {
    return __builtin_bit_cast(float, (unsigned int)u << 16);
}

__device__ __forceinline__ float softplus_f(float x) {
    return fmaxf(x, 0.0f) + __logf(1.0f + __expf(-fabsf(x)));
}

__device__ __forceinline__ float smooth_l1_f(float d) {
    float ad = fabsf(d);
    return (ad < BETA) ? (0.5f / BETA) * d * d : (ad - 0.5f * BETA);
}

// ---------------------------------------------------------------------------
// Kernel 1: adjacency (int32 ZxZ) -> bf16 mask (ZxZ, K-contig) + invdeg + hasnb
__global__ void k_prep(const int* __restrict__ adj, unsigned short* __restrict__ maskbf,
                       float* __restrict__ invdeg, float* __restrict__ hasnb, int Z) {
    int z = blockIdx.x;
    int t = threadIdx.x;
    const int* row = adj + (size_t)z * Z;
    unsigned short* mrow = maskbf + (size_t)z * Z;
    int cnt = 0;
    for (int n = t; n < Z; n += blockDim.x) {
        int a = (row[n] > 0);
        mrow[n] = a ? (unsigned short)0x3F80 : (unsigned short)0;  // bf16 1.0 / 0.0
        cnt += a;
    }
    for (int o = 32; o; o >>= 1) cnt += __shfl_down(cnt, o);
    __shared__ int rs[4];
    int lane = t & 63, wave = t >> 6;
    if (lane == 0) rs[wave] = cnt;
    __syncthreads();
    if (t == 0) {
        int deg = rs[0] + rs[1] + rs[2] + rs[3];
        invdeg[z] = (deg > 0) ? 1.0f / (float)deg : 1.0f;
        hasnb[z]  = (deg > 0) ? 1.0f : 0.0f;
    }
}

// ---------------------------------------------------------------------------
// Kernel 2: fp32 -> bf16 (RN), 8 elems/thread, vectorized
__global__ void k_conv(const float* __restrict__ src, uint4* __restrict__ dst, long n8) {
    long i = (long)blockIdx.x * blockDim.x + threadIdx.x;
    long stride = (long)gridDim.x * blockDim.x;
    for (; i < n8; i += stride) {
        const float4* s = (const float4*)(src + i * 8);
        float4 a = s[0], b = s[1];
        uint4 o;
        o.x = (unsigned)f2bf_rn(a.x) | ((unsigned)f2bf_rn(a.y) << 16);
        o.y = (unsigned)f2bf_rn(a.z) | ((unsigned)f2bf_rn(a.w) << 16);
        o.z = (unsigned)f2bf_rn(b.x) | ((unsigned)f2bf_rn(b.y) << 16);
        o.w = (unsigned)f2bf_rn(b.z) | ((unsigned)f2bf_rn(b.w) << 16);
        dst[i] = o;
    }
}

// ---------------------------------------------------------------------------
// Kernel 3: 256x256 bf16 GEMM, 8-phase schedule (T2 swizzle + T3/T4 counted
// vmcnt + T5 setprio), T1 XCD swizzle, fused softplus/smooth-L1 epilogue.
//
// Half-tile layout (128 rows x 64 cols each, interleaved so each C-quadrant
// phase reads exactly one A-half + one B-half):
//   A-half h, halfrow hr  <->  block row (hr>>6)*128 + h*64 + (hr&63)
//   B-half h, halfrow hr  <->  block col (hr>>5)*64  + h*32 + (hr&31)
// Wave wm owns block rows wm*128..wm*128+127 ; wave wn owns cols wn*64..+63.
// T2 swizzle: 16B col-slot s at row hr physically lives at slot s^(hr&7);
// staging pre-swizzles the GLOBAL source column, LDS dest stays t-linear.
__global__ __launch_bounds__(NT, 2) void k_gemm(
    const unsigned short* __restrict__ Abf,   // [M][K] bf16 ctemps
    const unsigned short* __restrict__ Bbf,   // [N][K] bf16 mask
    const float* __restrict__ preds,
    const float* __restrict__ targets,
    const float* __restrict__ invdeg,
    const float* __restrict__ hasnb,
    float* __restrict__ partials,
    int M, int N, int K)
{
    __shared__ unsigned short As[2][2][128 * 64];   // [buf][half][hr*64 + col]
    __shared__ unsigned short Bs[2][2][128 * 64];

    const int nwg = gridDim.x;
    const int ob = blockIdx.x;
    const int bid = (nwg % 8 == 0) ? ((ob % 8) * (nwg / 8) + ob / 8) : ob;  // T1
    const int ntiles = N / BN;
    const int mt = bid / ntiles;
    const int nt = bid % ntiles;
    const int row0 = mt * BM;
    const int col0 = nt * BN;
    const int t = threadIdx.x;
    const int lane = t & 63;
    const int wave = t >> 6;
    const int wm = wave >> 2;             // 2x4 wave grid
    const int wn = wave & 3;
    const int fr = lane & 15;
    const int fq = lane >> 4;
    const int fr7 = fr & 7;

    // staging decomposition: thread t -> (tr, tc); source col-slot pre-swizzled
    const int tr = t >> 3;                // 0..63
    const int tc = t & 7;                 // 16B slot 0..7
    const int cs = tc ^ (tr & 7);         // swizzled global col-slot

    f32x4 acc[8][4];
#pragma unroll
    for (int m = 0; m < 8; ++m)
#pragma unroll
        for (int n = 0; n < 4; ++n)
            acc[m][n] = (f32x4){0.f, 0.f, 0.f, 0.f};

    const unsigned short* Ab = Abf + (size_t)row0 * K;
    const unsigned short* Bb = Bbf + (size_t)col0 * K;

#define STAGE_A(buf, h, kt) do {                                                             \
    _Pragma("unroll")                                                                        \
    for (int r_ = 0; r_ < 2; ++r_)                                                           \
        __builtin_amdgcn_global_load_lds(                                                    \
            (const AS1 void*)(Ab + (size_t)(r_ * 128 + (h) * 64 + tr) * K + (kt) * BK + cs * 8), \
            (AS3 void*)(&As[buf][h][(r_ * 64 + tr) * 64 + tc * 8]), 16, 0, 0);               \
} while (0)

#define STAGE_B(buf, h, kt) do {                                                             \
    _Pragma("unroll")                                                                        \
    for (int r_ = 0; r_ < 2; ++r_)                                                           \
        __builtin_amdgcn_global_load_lds(                                                    \
            (const AS1 void*)(Bb + (size_t)((r_ * 2 + (tr >> 5)) * 64 + (h) * 32 + (tr & 31)) * K + (kt) * BK + cs * 8), \
            (AS3 void*)(&Bs[buf][h][(r_ * 64 + tr) * 64 + tc * 8]), 16, 0, 0);               \
} while (0)

    bf16x8 af[4][2];   // A frags of current A-half: [mi][kk]
    bf16x8 bv[2][2];   // B frags of current B-half: [ni][kk]

#define LOAD_AF(buf, mq) do {                                                                \
    _Pragma("unroll")                                                                        \
    for (int mi_ = 0; mi_ < 4; ++mi_)                                                        \
    _Pragma("unroll")                                                                        \
    for (int kk_ = 0; kk_ < 2; ++kk_)                                                        \
        af[mi_][kk_] = *(const bf16x8*)&As[buf][mq][(wm * 64 + mi_ * 16 + fr) * 64 +         \
                                                    (((kk_ * 4 + fq) ^ fr7) * 8)];           \
} while (0)

#define LOAD_BF(buf, nq) do {                                                                \
    _Pragma("unroll")                                                                        \
    for (int ni_ = 0; ni_ < 2; ++ni_)                                                        \
    _Pragma("unroll")                                                                        \
    for (int kk_ = 0; kk_ < 2; ++kk_)                                                        \
        bv[ni_][kk_] = *(const bf16x8*)&Bs[buf][nq][(wn * 32 + ni_ * 16 + fr) * 64 +         \
                                                    (((kk_ * 4 + fq) ^ fr7) * 8)];           \
} while (0)

#define MFMA_Q(mq, nq) do {                                                                  \
    __builtin_amdgcn_s_setprio(1);                                                           \
    _Pragma("unroll")                                                                        \
    for (int kk_ = 0; kk_ < 2; ++kk_)                                                        \
    _Pragma("unroll")                                                                        \
    for (int mi_ = 0; mi_ < 4; ++mi_)                                                        \
    _Pragma("unroll")                                                                        \
    for (int ni_ = 0; ni_ < 2; ++ni_)                                                        \
        acc[(mq) * 4 + mi_][(nq) * 2 + ni_] = __builtin_amdgcn_mfma_f32_16x16x32_bf16(       \
            af[mi_][kk_], bv[ni_][kk_], acc[(mq) * 4 + mi_][(nq) * 2 + ni_], 0, 0, 0);       \
    __builtin_amdgcn_s_setprio(0);                                                           \
} while (0)

    const int nk = K / BK;
    // Prologue: stage tile 0 (order A0,B0,A1,B1 = per-phase stage order)
    STAGE_A(0, 0, 0); STAGE_B(0, 0, 0); STAGE_A(0, 1, 0); STAGE_B(0, 1, 0);

    int cur = 0;
    for (int ti = 0; ti < nk - 1; ++ti) {
        const int nb = cur ^ 1;
        // P0: quadrant (A0,B0)
        STAGE_A(nb, 0, ti + 1);
        WAITV6();                 // retires A0,B0 of tile ti (FIFO)
        BARRIER();
        LOAD_AF(cur, 0); LOAD_BF(cur, 0);
        MFMA_Q(0, 0);
        BARRIER();
        // P1: quadrant (A0,B1) — reuse af
        STAGE_B(nb, 0, ti + 1);
        WAITV4();                 // retires A1,B1 of tile ti
        BARRIER();
        LOAD_BF(cur, 1);
        MFMA_Q(0, 1);
        BARRIER();
        // P2: quadrant (A1,B1) — reuse bv
        STAGE_A(nb, 1, ti + 1);
        BARRIER();
        LOAD_AF(cur, 1);
        MFMA_Q(1, 1);
        BARRIER();
        // P3: quadrant (A1,B0) — reuse af
        STAGE_B(nb, 1, ti + 1);
        BARRIER();
        LOAD_BF(cur, 0);
        MFMA_Q(1, 0);
        BARRIER();
        cur = nb;
    }
    // Last tile: no staging; drain 4 -> 0
    WAITV4();
    BARRIER();
    LOAD_AF(cur, 0); LOAD_BF(cur, 0);
    MFMA_Q(0, 0);
    WAITV0();
    BARRIER();
    LOAD_BF(cur, 1);
    MFMA_Q(0, 1);
    LOAD_AF(cur, 1);
    MFMA_Q(1, 1);
    LOAD_BF(cur, 0);
    MFMA_Q(1, 0);

#undef STAGE_A
#undef STAGE_B
#undef LOAD_AF
#undef LOAD_BF
#undef MFMA_Q

    // Fused epilogue. C/D frag layout: col=lane&15, row=(lane>>4)*4+reg.
    // block row = wm*128 + (m>>2)*64 + (m&3)*16 + fq*4 + j
    // block col = wn*64  + (n>>1)*32 + (n&1)*16 + fr
    float vsum = 0.f, ssum = 0.f;
#pragma unroll
    for (int n = 0; n < 4; ++n) {
        const int z = col0 + wn * 64 + (n >> 1) * 32 + (n & 1) * 16 + fr;
        const float idg = invdeg[z];
        const float hnb = hasnb[z];
#pragma unroll
        for (int m = 0; m < 8; ++m) {
            const int rb = row0 + wm * 128 + (m >> 2) * 64 + (m & 3) * 16 + fq * 4;
#pragma unroll
            for (int j = 0; j < 4; ++j) {
                const size_t idx = (size_t)(rb + j) * N + z;
                float avg = acc[m][n][j] * idg;
                float c = bf2f(Abf[idx]);          // bf16 ctemps (saves 1/3 fetch)
                float p = preds[idx];
                float tg = targets[idx];
                float x = (c - avg) * (p - c);
                vsum += softplus_f(x) * hnb;
                ssum += smooth_l1_f(p - tg);
            }
        }
    }
    for (int o = 32; o; o >>= 1) { vsum += __shfl_down(vsum, o); ssum += __shfl_down(ssum, o); }
    __shared__ float rv[8], rsm[8];
    if (lane == 0) { rv[wave] = vsum; rsm[wave] = ssum; }
    __syncthreads();
    if (t == 0) {
        float v = 0.f, s = 0.f;
#pragma unroll
        for (int w = 0; w < 8; ++w) { v += rv[w]; s += rsm[w]; }
        partials[2 * (size_t)ob]     = v;
        partials[2 * (size_t)ob + 1] = s;
    }
}

// ---------------------------------------------------------------------------
// Kernel 4: deterministic fixed-order final reduction
__global__ void k_finalize(const float* __restrict__ partials, int nblk,
                           float* __restrict__ out, float invBZ) {
    __shared__ float sv[256], ss[256];
    int t = threadIdx.x;
    float v = 0.f, s = 0.f;
    for (int i = t; i < nblk; i += 256) { v += partials[2 * (size_t)i]; s += partials[2 * (size_t)i + 1]; }
    sv[t] = v; ss[t] = s;
    __syncthreads();
    for (int o = 128; o; o >>= 1) {
        if (t < o) { sv[t] += sv[t + o]; ss[t] += ss[t + o]; }
        __syncthreads();
    }
    if (t == 0) {
        float phys = sv[0] * invBZ;
        float pred = ss[0] * invBZ;
        out[0] = pred + LAMBDA_PHY * phys;
        out[1] = phys;
    }
}

// ---------------------------------------------------------------------------
// Fallback path (only if ws too small / odd shapes): fp32, atomics into ws[0..1]
__global__ void k_zero2(float* p) { if (threadIdx.x < 2) p[threadIdx.x] = 0.f; }

__global__ void k_fallback(const float* __restrict__ preds, const float* __restrict__ targets,
                           const float* __restrict__ ctemps, const int* __restrict__ adj,
                           float* __restrict__ acc2, int B, int Z) {
    extern __shared__ float crow[];
    int nzb = (Z + 255) / 256;
    int b = blockIdx.x / nzb;
    int zb = blockIdx.x % nzb;
    int t = threadIdx.x;
    const float* cr = ctemps + (size_t)b * Z;
    for (int n = t; n < Z; n += 256) crow[n] = cr[n];
    __syncthreads();
    int z = zb * 256 + t;
    float vsum = 0.f, ssum = 0.f;
    if (z < Z) {
        const int* arow = adj + (size_t)z * Z;
        float sum = 0.f; int deg = 0;
        for (int n = 0; n < Z; ++n) {
            if (arow[n] > 0) { sum += crow[n]; ++deg; }
        }
        float avg = (deg > 0) ? sum / (float)deg : 0.f;
        float c = crow[z];
        size_t idx = (size_t)b * Z + z;
        float p = preds[idx];
        float x = (c - avg) * (p - c);
        vsum = (deg > 0) ? softplus_f(x) : 0.f;
        ssum = smooth_l1_f(p - targets[idx]);
    }
    for (int o = 32; o; o >>= 1) { vsum += __shfl_down(vsum, o); ssum += __shfl_down(ssum, o); }
    __shared__ float rv[4], rs2[4];
    int lane = t & 63, wave = t >> 6;
    if (lane == 0) { rv[wave] = vsum; rs2[wave] = ssum; }
    __syncthreads();
    if (t == 0) {
        atomicAdd(&acc2[0], rv[0] + rv[1] + rv[2] + rv[3]);
        atomicAdd(&acc2[1], rs2[0] + rs2[1] + rs2[2] + rs2[3]);
    }
}

// ---------------------------------------------------------------------------
extern "C" void kernel_launch(void* const* d_in, const int* in_sizes, int n_in,
                              void* d_out, int out_size, void* d_ws, size_t ws_size,
                              hipStream_t stream) {
    const float* preds   = (const float*)d_in[0];
    const float* targets = (const float*)d_in[1];
    const float* ctemps  = (const float*)d_in[2];
    const int*   adj     = (const int*)d_in[3];
    float* out = (float*)d_out;

    long zz = in_sizes[3];
    int Z = (int)llround(sqrt((double)zz));
    int B = in_sizes[1] / Z;

    size_t off = 0;
    size_t maskOff = off; off += (size_t)Z * Z * 2;
    size_t cbfOff  = off; off += (size_t)B * Z * 2;
    size_t idgOff  = off; off += (size_t)Z * 4;
    size_t hnbOff  = off; off += (size_t)Z * 4;
    int nblk = (Z > 0 && B > 0 && (B % BM) == 0 && (Z % BN) == 0) ? (B / BM) * (Z / BN) : 0;
    size_t partOff = off; off += (size_t)(nblk > 0 ? nblk : 1) * 2 * 4;

    bool main_ok = (B % BM == 0) && (Z % BN == 0) && (Z % BK == 0) && (ws_size >= off);

    float invBZ = (float)(1.0 / ((double)B * (double)Z));

    if (main_ok) {
        char* ws = (char*)d_ws;
        unsigned short* maskbf = (unsigned short*)(ws + maskOff);
        unsigned short* cbf    = (unsigned short*)(ws + cbfOff);
        float* idg      = (float*)(ws + idgOff);
        float* hnb      = (float*)(ws + hnbOff);
        float* partials = (float*)(ws + partOff);

        k_prep<<<Z, 256, 0, stream>>>(adj, maskbf, idg, hnb, Z);
        long n8 = (long)B * Z / 8;
        k_conv<<<2048, 256, 0, stream>>>(ctemps, (uint4*)cbf, n8);
        k_gemm<<<nblk, NT, 0, stream>>>(cbf, maskbf, preds, targets, idg, hnb, partials, B, Z, Z);
        k_finalize<<<1, 256, 0, stream>>>(partials, nblk, out, invBZ);
    } else {
        float* acc2 = (float*)d_ws;
        k_zero2<<<1, 64, 0, stream>>>(acc2);
        int nzb = (Z + 255) / 256;
        k_fallback<<<B * nzb, 256, (size_t)Z * 4, stream>>>(preds, targets, ctemps, adj, acc2, B, Z);
        k_finalize<<<1, 256, 0, stream>>>(acc2, 1, out, invBZ);
    }
}

// Round 4
// 319.584 us; speedup vs baseline: 1.2635x; 1.1906x over previous
//
#include <hip/hip_runtime.h>
#include <hip/hip_bf16.h>
#include <cmath>

#define BETA 0.3f
#define LAMBDA_PHY 0.15f

#define BM 256
#define BN 256
#define BK 64
#define NT 512

typedef __bf16 bf16x8 __attribute__((ext_vector_type(8)));
typedef float f32x4 __attribute__((ext_vector_type(4)));

#define AS1 __attribute__((address_space(1)))
#define AS3 __attribute__((address_space(3)))

#define FENCE() asm volatile("" ::: "memory")
#define BARRIER() do { FENCE(); __builtin_amdgcn_s_barrier(); FENCE(); } while (0)
#define WAITV4() asm volatile("s_waitcnt vmcnt(4)" ::: "memory")
#define WAITV0() asm volatile("s_waitcnt vmcnt(0)" ::: "memory")

__device__ __forceinline__ unsigned short f2bf_rn(float f) {
    unsigned int u = __builtin_bit_cast(unsigned int, f);
    return (unsigned short)((u + 0x7FFFu + ((u >> 16) & 1u)) >> 16);
}

__device__ __forceinline__ float bf2f(unsigned short u) {
    return __builtin_bit_cast(float, (unsigned int)u << 16);
}

__device__ __forceinline__ float softplus_f(float x) {
    return fmaxf(x, 0.0f) + __logf(1.0f + __expf(-fabsf(x)));
}

__device__ __forceinline__ float smooth_l1_f(float d) {
    float ad = fabsf(d);
    return (ad < BETA) ? (0.5f / BETA) * d * d : (ad - 0.5f * BETA);
}

// ---------------------------------------------------------------------------
// Kernel 1: adjacency (int32 ZxZ) -> bf16 mask (ZxZ, K-contig) + invdeg + hasnb
__global__ void k_prep(const int* __restrict__ adj, unsigned short* __restrict__ maskbf,
                       float* __restrict__ invdeg, float* __restrict__ hasnb, int Z) {
    int z = blockIdx.x;
    int t = threadIdx.x;
    const int* row = adj + (size_t)z * Z;
    unsigned short* mrow = maskbf + (size_t)z * Z;
    int cnt = 0;
    for (int n = t; n < Z; n += blockDim.x) {
        int a = (row[n] > 0);
        mrow[n] = a ? (unsigned short)0x3F80 : (unsigned short)0;  // bf16 1.0 / 0.0
        cnt += a;
    }
    for (int o = 32; o; o >>= 1) cnt += __shfl_down(cnt, o);
    __shared__ int rs[4];
    int lane = t & 63, wave = t >> 6;
    if (lane == 0) rs[wave] = cnt;
    __syncthreads();
    if (t == 0) {
        int deg = rs[0] + rs[1] + rs[2] + rs[3];
        invdeg[z] = (deg > 0) ? 1.0f / (float)deg : 1.0f;
        hasnb[z]  = (deg > 0) ? 1.0f : 0.0f;
    }
}

// ---------------------------------------------------------------------------
// Kernel 2: fp32 -> bf16 (RN), 8 elems/thread, vectorized
__global__ void k_conv(const float* __restrict__ src, uint4* __restrict__ dst, long n8) {
    long i = (long)blockIdx.x * blockDim.x + threadIdx.x;
    long stride = (long)gridDim.x * blockDim.x;
    for (; i < n8; i += stride) {
        const float4* s = (const float4*)(src + i * 8);
        float4 a = s[0], b = s[1];
        uint4 o;
        o.x = (unsigned)f2bf_rn(a.x) | ((unsigned)f2bf_rn(a.y) << 16);
        o.y = (unsigned)f2bf_rn(a.z) | ((unsigned)f2bf_rn(a.w) << 16);
        o.z = (unsigned)f2bf_rn(b.x) | ((unsigned)f2bf_rn(b.y) << 16);
        o.w = (unsigned)f2bf_rn(b.z) | ((unsigned)f2bf_rn(b.w) << 16);
        dst[i] = o;
    }
}

// ---------------------------------------------------------------------------
// Kernel 3: 256x256 bf16 GEMM, 8-phase schedule (T2 swizzle + T3/T4 counted
// vmcnt + T5 setprio), T1 XCD swizzle, fused softplus/smooth-L1 epilogue.
// ds_reads hoisted PRE-barrier (m201 micro-order); stage order A0,B0,B1,A1
// gives every vmcnt(4) wait >=2 phases of issue-to-wait slack.
// NOTE: single-arg launch_bounds — LDS already limits to 1 block/CU, and the
// (NT,2) hint capped VGPR at 128 => 54 MB/dispatch scratch spill (round 3).
__global__ __launch_bounds__(NT) void k_gemm(
    const unsigned short* __restrict__ Abf,   // [M][K] bf16 ctemps
    const unsigned short* __restrict__ Bbf,   // [N][K] bf16 mask
    const float* __restrict__ preds,
    const float* __restrict__ targets,
    const float* __restrict__ invdeg,
    const float* __restrict__ hasnb,
    float* __restrict__ partials,
    int M, int N, int K)
{
    __shared__ unsigned short As[2][2][128 * 64];   // [buf][half][hr*64 + col]
    __shared__ unsigned short Bs[2][2][128 * 64];

    const int nwg = gridDim.x;
    const int ob = blockIdx.x;
    const int bid = (nwg % 8 == 0) ? ((ob % 8) * (nwg / 8) + ob / 8) : ob;  // T1
    const int ntiles = N / BN;
    const int mt = bid / ntiles;
    const int nt = bid % ntiles;
    const int row0 = mt * BM;
    const int col0 = nt * BN;
    const int t = threadIdx.x;
    const int lane = t & 63;
    const int wave = t >> 6;
    const int wm = wave >> 2;             // 2x4 wave grid
    const int wn = wave & 3;
    const int fr = lane & 15;
    const int fq = lane >> 4;
    const int fr7 = fr & 7;

    // staging decomposition: thread t -> (tr, tc); source col-slot pre-swizzled
    const int tr = t >> 3;                // 0..63
    const int tc = t & 7;                 // 16B slot 0..7
    const int cs = tc ^ (tr & 7);         // swizzled global col-slot

    f32x4 acc[8][4];
#pragma unroll
    for (int m = 0; m < 8; ++m)
#pragma unroll
        for (int n = 0; n < 4; ++n)
            acc[m][n] = (f32x4){0.f, 0.f, 0.f, 0.f};

    const unsigned short* Ab = Abf + (size_t)row0 * K;
    const unsigned short* Bb = Bbf + (size_t)col0 * K;

#define STAGE_A(buf, h, kt) do {                                                             \
    _Pragma("unroll")                                                                        \
    for (int r_ = 0; r_ < 2; ++r_)                                                           \
        __builtin_amdgcn_global_load_lds(                                                    \
            (const AS1 void*)(Ab + (size_t)(r_ * 128 + (h) * 64 + tr) * K + (kt) * BK + cs * 8), \
            (AS3 void*)(&As[buf][h][(r_ * 64 + tr) * 64 + tc * 8]), 16, 0, 0);               \
} while (0)

#define STAGE_B(buf, h, kt) do {                                                             \
    _Pragma("unroll")                                                                        \
    for (int r_ = 0; r_ < 2; ++r_)                                                           \
        __builtin_amdgcn_global_load_lds(                                                    \
            (const AS1 void*)(Bb + (size_t)((r_ * 2 + (tr >> 5)) * 64 + (h) * 32 + (tr & 31)) * K + (kt) * BK + cs * 8), \
            (AS3 void*)(&Bs[buf][h][(r_ * 64 + tr) * 64 + tc * 8]), 16, 0, 0);               \
} while (0)

    bf16x8 af[4][2];   // A frags of current A-half: [mi][kk]
    bf16x8 bv[2][2];   // B frags of current B-half: [ni][kk]

#define LOAD_AF(buf, mq) do {                                                                \
    _Pragma("unroll")                                                                        \
    for (int mi_ = 0; mi_ < 4; ++mi_)                                                        \
    _Pragma("unroll")                                                                        \
    for (int kk_ = 0; kk_ < 2; ++kk_)                                                        \
        af[mi_][kk_] = *(const bf16x8*)&As[buf][mq][(wm * 64 + mi_ * 16 + fr) * 64 +         \
                                                    (((kk_ * 4 + fq) ^ fr7) * 8)];           \
} while (0)

#define LOAD_BF(buf, nq) do {                                                                \
    _Pragma("unroll")                                                                        \
    for (int ni_ = 0; ni_ < 2; ++ni_)                                                        \
    _Pragma("unroll")                                                                        \
    for (int kk_ = 0; kk_ < 2; ++kk_)                                                        \
        bv[ni_][kk_] = *(const bf16x8*)&Bs[buf][nq][(wn * 32 + ni_ * 16 + fr) * 64 +         \
                                                    (((kk_ * 4 + fq) ^ fr7) * 8)];           \
} while (0)

#define MFMA_Q(mq, nq) do {                                                                  \
    __builtin_amdgcn_s_setprio(1);                                                           \
    _Pragma("unroll")                                                                        \
    for (int kk_ = 0; kk_ < 2; ++kk_)                                                        \
    _Pragma("unroll")                                                                        \
    for (int mi_ = 0; mi_ < 4; ++mi_)                                                        \
    _Pragma("unroll")                                                                        \
    for (int ni_ = 0; ni_ < 2; ++ni_)                                                        \
        acc[(mq) * 4 + mi_][(nq) * 2 + ni_] = __builtin_amdgcn_mfma_f32_16x16x32_bf16(       \
            af[mi_][kk_], bv[ni_][kk_], acc[(mq) * 4 + mi_][(nq) * 2 + ni_], 0, 0, 0);       \
    __builtin_amdgcn_s_setprio(0);                                                           \
} while (0)

    const int nk = K / BK;
    // Prologue: stage tile 0 in order A0,B0,B1,A1; retire A0,B0 before loop.
    STAGE_A(0, 0, 0); STAGE_B(0, 0, 0); STAGE_B(0, 1, 0); STAGE_A(0, 1, 0);
    WAITV4();
    BARRIER();

    int cur = 0;
    for (int ti = 0; ti < nk - 1; ++ti) {
        const int nb = cur ^ 1;
        // R0: quadrant (A0,B0). Reads pre-barrier; stage (ti+1,A0).
        LOAD_AF(cur, 0); LOAD_BF(cur, 0);
        STAGE_A(nb, 0, ti + 1);
        WAITV4();                 // retires (ti,B1) — read at R1
        BARRIER();
        MFMA_Q(0, 0);
        BARRIER();
        // R1: quadrant (A0,B1) — af reused; stage (ti+1,B0).
        LOAD_BF(cur, 1);
        STAGE_B(nb, 0, ti + 1);
        WAITV4();                 // retires (ti,A1) — read at R2
        BARRIER();
        MFMA_Q(0, 1);
        BARRIER();
        // R2: quadrant (A1,B1) — bv reused; stage (ti+1,B1).
        LOAD_AF(cur, 1);
        STAGE_B(nb, 1, ti + 1);
        BARRIER();
        MFMA_Q(1, 1);
        BARRIER();
        // R3: quadrant (A1,B0); stage (ti+1,A1).
        LOAD_BF(cur, 0);
        STAGE_A(nb, 1, ti + 1);
        WAITV4();                 // retires (ti+1,A0),(ti+1,B0) — read at next R0
        BARRIER();
        MFMA_Q(1, 0);
        BARRIER();
        cur = nb;
    }
    // Tail tile: drain everything once, then compute all 4 quadrants.
    WAITV0();
    BARRIER();
    LOAD_AF(cur, 0); LOAD_BF(cur, 0);
    MFMA_Q(0, 0);
    LOAD_BF(cur, 1);
    MFMA_Q(0, 1);
    LOAD_AF(cur, 1);
    MFMA_Q(1, 1);
    LOAD_BF(cur, 0);
    MFMA_Q(1, 0);

#undef STAGE_A
#undef STAGE_B
#undef LOAD_AF
#undef LOAD_BF
#undef MFMA_Q

    // Fused epilogue. C/D frag layout: col=lane&15, row=(lane>>4)*4+reg.
    // block row = wm*128 + (m>>2)*64 + (m&3)*16 + fq*4 + j
    // block col = wn*64  + (n>>1)*32 + (n&1)*16 + fr
    float vsum = 0.f, ssum = 0.f;
#pragma unroll
    for (int n = 0; n < 4; ++n) {
        const int z = col0 + wn * 64 + (n >> 1) * 32 + (n & 1) * 16 + fr;
        const float idg = invdeg[z];
        const float hnb = hasnb[z];
#pragma unroll
        for (int m = 0; m < 8; ++m) {
            const int rb = row0 + wm * 128 + (m >> 2) * 64 + (m & 3) * 16 + fq * 4;
#pragma unroll
            for (int j = 0; j < 4; ++j) {
                const size_t idx = (size_t)(rb + j) * N + z;
                float avg = acc[m][n][j] * idg;
                float c = bf2f(Abf[idx]);          // bf16 ctemps (saves 1/3 fetch)
                float p = preds[idx];
                float tg = targets[idx];
                float x = (c - avg) * (p - c);
                vsum += softplus_f(x) * hnb;
                ssum += smooth_l1_f(p - tg);
            }
        }
    }
    for (int o = 32; o; o >>= 1) { vsum += __shfl_down(vsum, o); ssum += __shfl_down(ssum, o); }
    __shared__ float rv[8], rsm[8];
    if (lane == 0) { rv[wave] = vsum; rsm[wave] = ssum; }
    __syncthreads();
    if (t == 0) {
        float v = 0.f, s = 0.f;
#pragma unroll
        for (int w = 0; w < 8; ++w) { v += rv[w]; s += rsm[w]; }
        partials[2 * (size_t)ob]     = v;
        partials[2 * (size_t)ob + 1] = s;
    }
}

// ---------------------------------------------------------------------------
// Kernel 4: deterministic fixed-order final reduction
__global__ void k_finalize(const float* __restrict__ partials, int nblk,
                           float* __restrict__ out, float invBZ) {
    __shared__ float sv[256], ss[256];
    int t = threadIdx.x;
    float v = 0.f, s = 0.f;
    for (int i = t; i < nblk; i += 256) { v += partials[2 * (size_t)i]; s += partials[2 * (size_t)i + 1]; }
    sv[t] = v; ss[t] = s;
    __syncthreads();
    for (int o = 128; o; o >>= 1) {
        if (t < o) { sv[t] += sv[t + o]; ss[t] += ss[t + o]; }
        __syncthreads();
    }
    if (t == 0) {
        float phys = sv[0] * invBZ;
        float pred = ss[0] * invBZ;
        out[0] = pred + LAMBDA_PHY * phys;
        out[1] = phys;
    }
}

// ---------------------------------------------------------------------------
// Fallback path (only if ws too small / odd shapes): fp32, atomics into ws[0..1]
__global__ void k_zero2(float* p) { if (threadIdx.x < 2) p[threadIdx.x] = 0.f; }

__global__ void k_fallback(const float* __restrict__ preds, const float* __restrict__ targets,
                           const float* __restrict__ ctemps, const int* __restrict__ adj,
                           float* __restrict__ acc2, int B, int Z) {
    extern __shared__ float crow[];
    int nzb = (Z + 255) / 256;
    int b = blockIdx.x / nzb;
    int zb = blockIdx.x % nzb;
    int t = threadIdx.x;
    const float* cr = ctemps + (size_t)b * Z;
    for (int n = t; n < Z; n += 256) crow[n] = cr[n];
    __syncthreads();
    int z = zb * 256 + t;
    float vsum = 0.f, ssum = 0.f;
    if (z < Z) {
        const int* arow = adj + (size_t)z * Z;
        float sum = 0.f; int deg = 0;
        for (int n = 0; n < Z; ++n) {
            if (arow[n] > 0) { sum += crow[n]; ++deg; }
        }
        float avg = (deg > 0) ? sum / (float)deg : 0.f;
        float c = crow[z];
        size_t idx = (size_t)b * Z + z;
        float p = preds[idx];
        float x = (c - avg) * (p - c);
        vsum = (deg > 0) ? softplus_f(x) : 0.f;
        ssum = smooth_l1_f(p - targets[idx]);
    }
    for (int o = 32; o; o >>= 1) { vsum += __shfl_down(vsum, o); ssum += __shfl_down(ssum, o); }
    __shared__ float rv[4], rs2[4];
    int lane = t & 63, wave = t >> 6;
    if (lane == 0) { rv[wave] = vsum; rs2[wave] = ssum; }
    __syncthreads();
    if (t == 0) {
        atomicAdd(&acc2[0], rv[0] + rv[1] + rv[2] + rv[3]);
        atomicAdd(&acc2[1], rs2[0] + rs2[1] + rs2[2] + rs2[3]);
    }
}

// ---------------------------------------------------------------------------
extern "C" void kernel_launch(void* const* d_in, const int* in_sizes, int n_in,
                              void* d_out, int out_size, void* d_ws, size_t ws_size,
                              hipStream_t stream) {
    const float* preds   = (const float*)d_in[0];
    const float* targets = (const float*)d_in[1];
    const float* ctemps  = (const float*)d_in[2];
    const int*   adj     = (const int*)d_in[3];
    float* out = (float*)d_out;

    long zz = in_sizes[3];
    int Z = (int)llround(sqrt((double)zz));
    int B = in_sizes[1] / Z;

    size_t off = 0;
    size_t maskOff = off; off += (size_t)Z * Z * 2;
    size_t cbfOff  = off; off += (size_t)B * Z * 2;
    size_t idgOff  = off; off += (size_t)Z * 4;
    size_t hnbOff  = off; off += (size_t)Z * 4;
    int nblk = (Z > 0 && B > 0 && (B % BM) == 0 && (Z % BN) == 0) ? (B / BM) * (Z / BN) : 0;
    size_t partOff = off; off += (size_t)(nblk > 0 ? nblk : 1) * 2 * 4;

    bool main_ok = (B % BM == 0) && (Z % BN == 0) && (Z % BK == 0) && (ws_size >= off);

    float invBZ = (float)(1.0 / ((double)B * (double)Z));

    if (main_ok) {
        char* ws = (char*)d_ws;
        unsigned short* maskbf = (unsigned short*)(ws + maskOff);
        unsigned short* cbf    = (unsigned short*)(ws + cbfOff);
        float* idg      = (float*)(ws + idgOff);
        float* hnb      = (float*)(ws + hnbOff);
        float* partials = (float*)(ws + partOff);

        k_prep<<<Z, 256, 0, stream>>>(adj, maskbf, idg, hnb, Z);
        long n8 = (long)B * Z / 8;
        k_conv<<<2048, 256, 0, stream>>>(ctemps, (uint4*)cbf, n8);
        k_gemm<<<nblk, NT, 0, stream>>>(cbf, maskbf, preds, targets, idg, hnb, partials, B, Z, Z);
        k_finalize<<<1, 256, 0, stream>>>(partials, nblk, out, invBZ);
    } else {
        float* acc2 = (float*)d_ws;
        k_zero2<<<1, 64, 0, stream>>>(acc2);
        int nzb = (Z + 255) / 256;
        k_fallback<<<B * nzb, 256, (size_t)Z * 4, stream>>>(preds, targets, ctemps, adj, acc2, B, Z);
        k_finalize<<<1, 256, 0, stream>>>(acc2, 1, out, invBZ);
    }
}